// Round 5
// baseline (194.810 us; speedup 1.0000x reference)
//
#include <hip/hip_runtime.h>

using bf16 = __bf16;
typedef __bf16 bf16x2 __attribute__((ext_vector_type(2)));
typedef __bf16 bf16x4v __attribute__((ext_vector_type(4)));
typedef __bf16 bf16x8 __attribute__((ext_vector_type(8)));
typedef float f32x4 __attribute__((ext_vector_type(4)));
typedef float floatx4 __attribute__((ext_vector_type(4)));

#define MFMA16(a, b, c) __builtin_amdgcn_mfma_f32_16x16x32_bf16((a), (b), (c), 0, 0, 0)

__device__ __forceinline__ float exp2a(float x) {
  float r;
  asm("v_exp_f32 %0, %1" : "=v"(r) : "v"(x));
  return r;
}

// ---------------- cast fp32 -> bf16 (4 elems/thread) ----------------
__global__ __launch_bounds__(256) void cast_kernel(const float* __restrict__ in,
                                                   bf16* __restrict__ out, int n4) {
  int i = blockIdx.x * 256 + threadIdx.x;
  if (i >= n4) return;
  floatx4 v = *(const floatx4*)(in + (size_t)i * 4);
  bf16x4v o;
  #pragma unroll
  for (int j = 0; j < 4; ++j) o[j] = (bf16)v[j];
  *(bf16x4v*)(out + (size_t)i * 4) = o;
}

// ---------------- GEMM: C[M][N] = A[M][K] * B[N][K]^T ----------------
template <bool OUT_F32>
__global__ __launch_bounds__(256, 2) void gemm_bt(const bf16* __restrict__ A,
                                                  const bf16* __restrict__ B,
                                                  void* __restrict__ Cv,
                                                  int M, int N, int K) {
  __shared__ bf16 As[128 * 32];
  __shared__ bf16 Bs[128 * 32];
  const int t = threadIdx.x;
  const int l = t & 63;
  const int w = t >> 6;
  const int m0 = blockIdx.y * 128;
  const int n0 = blockIdx.x * 128;
  const int wr = (w >> 1) * 64;
  const int wc = (w & 1) * 64;
  const int lr = l & 15;
  const int lk = (l >> 4) * 8;

  f32x4 acc[4][4] = {};

  const int srow = t >> 2;
  const int scol = (t & 3) * 8;

  for (int k0 = 0; k0 < K; k0 += 32) {
    __syncthreads();
    #pragma unroll
    for (int j = 0; j < 2; ++j) {
      const bf16* ga = A + (size_t)(m0 + j * 64 + srow) * K + k0 + scol;
      __builtin_amdgcn_global_load_lds(
          (const __attribute__((address_space(1))) void*)ga,
          (__attribute__((address_space(3))) void*)(As + (j * 64 + srow) * 32 + scol),
          16, 0, 0);
      const bf16* gb = B + (size_t)(n0 + j * 64 + srow) * K + k0 + scol;
      __builtin_amdgcn_global_load_lds(
          (const __attribute__((address_space(1))) void*)gb,
          (__attribute__((address_space(3))) void*)(Bs + (j * 64 + srow) * 32 + scol),
          16, 0, 0);
    }
    __syncthreads();
    bf16x8 af[4], bfr[4];
    #pragma unroll
    for (int i = 0; i < 4; ++i) af[i] = *(const bf16x8*)(As + (wr + i * 16 + lr) * 32 + lk);
    #pragma unroll
    for (int i = 0; i < 4; ++i) bfr[i] = *(const bf16x8*)(Bs + (wc + i * 16 + lr) * 32 + lk);
    #pragma unroll
    for (int i = 0; i < 4; ++i)
      #pragma unroll
      for (int j = 0; j < 4; ++j)
        acc[i][j] = MFMA16(af[i], bfr[j], acc[i][j]);
  }

  const int cr0 = (l >> 4) * 4;
  const int cc = l & 15;
  #pragma unroll
  for (int i = 0; i < 4; ++i) {
    #pragma unroll
    for (int j = 0; j < 4; ++j) {
      int row = m0 + wr + i * 16 + cr0;
      int col = n0 + wc + j * 16 + cc;
      #pragma unroll
      for (int r = 0; r < 4; ++r) {
        if constexpr (OUT_F32)
          ((float*)Cv)[(size_t)(row + r) * N + col] = acc[i][j][r];
        else
          ((bf16*)Cv)[(size_t)(row + r) * N + col] = (bf16)acc[i][j][r];
      }
    }
  }
}

// ---------------- RoPE in-place on q,k of qkv [4096][3072] ----------------
__global__ __launch_bounds__(256) void rope_kernel(bf16* __restrict__ qkv,
                                                   const int* __restrict__ pos) {
  int idx = blockIdx.x * 256 + threadIdx.x;
  int i = idx & 31;
  int h = (idx >> 5) & 15;
  int row = idx >> 9;
  int s = row & 2047;
  float p = (float)pos[s];
  float freq = exp2f(-(float)i * (13.287712379549449f / 32.0f));
  float ang = p * freq;
  float sn, cs;
  sincosf(ang, &sn, &cs);
  size_t base = (size_t)row * 3072 + h * 64 + 2 * i;
  bf16x2 q = *(bf16x2*)(qkv + base);
  bf16x2 k = *(bf16x2*)(qkv + base + 1024);
  float q1 = (float)q[0], q2 = (float)q[1];
  float k1 = (float)k[0], k2 = (float)k[1];
  bf16x2 qo, ko;
  qo[0] = (bf16)(q1 * cs - q2 * sn);
  qo[1] = (bf16)(q1 * sn + q2 * cs);
  ko[0] = (bf16)(k1 * cs - k2 * sn);
  ko[1] = (bf16)(k1 * sn + k2 * cs);
  *(bf16x2*)(qkv + base) = qo;
  *(bf16x2*)(qkv + base + 1024) = ko;
}

// ---------------- causal flash attention v5: K-split x2 + partials ----------------
// grid: (S/128, B*H, 2). 256 thr = 4 waves; wave w owns q rows [q0+32w, q0+32w+32).
// z = blockIdx.z processes K-tiles kt = z, z+2, ... (interleaved for balance).
// Writes normalized partial O (bf16, attn layout) + (m,l) per row; combine merges.
__global__ __launch_bounds__(256, 4) void fa_causal(const bf16* __restrict__ qkv,
                                                    bf16* __restrict__ part0,
                                                    bf16* __restrict__ part1,
                                                    float2* __restrict__ ml) {
  const int bh = blockIdx.y;
  const int b = bh >> 4, h = bh & 15;
  const int q0 = ((int)gridDim.x - 1 - (int)blockIdx.x) * 128;  // heavy blocks first
  const int z = blockIdx.z;
  const int t = threadIdx.x, w = t >> 6, l = t & 63;
  const int lq = l & 15;
  const int g = l >> 4;
  const int lk = g * 8;
  const int swz = lq & 7;

  __shared__ bf16 Ks[2][64 * 64];   // K dbuf, source-XOR swizzled content
  __shared__ bf16 Vt[64 * 64];      // V^T single buffer, XOR swizzled
  __shared__ bf16 Ps[4][16 * 72];   // per-wave P^T / epilogue staging (16 rows)

  const size_t rs = 3072;
  const bf16* Qg = qkv + (size_t)(b * 2048) * rs + h * 64;
  const bf16* Kg = Qg + 1024;
  const bf16* Vg = Qg + 2048;

  const int qrow0 = q0 + w * 32;

  bf16x8 qfr[2][2];
  #pragma unroll
  for (int qi = 0; qi < 2; ++qi)
    #pragma unroll
    for (int kk = 0; kk < 2; ++kk)
      qfr[qi][kk] = *(const bf16x8*)(Qg + (size_t)(qrow0 + qi * 16 + lq) * rs + kk * 32 + lk);

  f32x4 o[4][2] = {};
  float mrow[2] = {-1e30f, -1e30f}, lrow[2] = {0.f, 0.f};
  const float SC = 0.125f * 1.44269504088896f;  // scale * log2(e)

  const int nkt = (q0 + 128) >> 6;
  const int krow_in = l >> 3;
  const int kcsrc = (l & 7) ^ krow_in;
  const int vk = t >> 2;           // 0..63 key row
  const int vd0 = (t & 3) * 16;    // d base
  const int vx = vd0 >> 4;

  bf16x8 va, vb2;

  #define STAGE_K(KT, BUF)                                                                \
    {                                                                                     \
      _Pragma("unroll")                                                                   \
      for (int c = 0; c < 2; ++c) {                                                       \
        const int rowbase = w * 16 + c * 8;                                               \
        const bf16* src = Kg + (size_t)((KT)*64 + rowbase + krow_in) * rs + kcsrc * 8;    \
        __builtin_amdgcn_global_load_lds(                                                 \
            (const __attribute__((address_space(1))) void*)src,                           \
            (__attribute__((address_space(3))) void*)(&Ks[BUF][rowbase * 64]), 16, 0, 0); \
      }                                                                                   \
    }
  #define LOAD_V(KT)                                                       \
    {                                                                      \
      const bf16* vsrc = Vg + (size_t)((KT)*64 + vk) * rs + vd0;           \
      va = *(const bf16x8*)(vsrc);                                         \
      vb2 = *(const bf16x8*)(vsrc + 8);                                    \
    }
  #define WRITE_V()                                                       \
    {                                                                     \
      _Pragma("unroll")                                                   \
      for (int e = 0; e < 8; ++e) {                                       \
        int pp = vk ^ (e << 3) ^ (vx << 4);                               \
        Vt[(vd0 + e) * 64 + pp] = va[e];                                  \
        Vt[(vd0 + 8 + e) * 64 + pp] = vb2[e];                             \
      }                                                                   \
    }

  STAGE_K(z, 0)
  LOAD_V(z)
  WRITE_V()
  __syncthreads();

  int cur = 0;
  for (int kt = z; kt < nkt; kt += 2) {
    const bool pf = (kt + 2 < nkt);
    if (pf) {
      LOAD_V(kt + 2)
      STAGE_K(kt + 2, cur ^ 1)
    }

    if (kt * 64 <= qrow0 + 31) {  // wave-uniform causal skip
      const bf16* Kc = Ks[cur];
      const bool full = (kt * 64 + 63 <= qrow0);  // no masking needed anywhere in wave

      f32x4 sc0[4] = {}, sc1[4] = {};
      __builtin_amdgcn_s_setprio(1);
      #pragma unroll
      for (int kf = 0; kf < 4; ++kf) {
        const int krow = kf * 16 + lq;
        bf16x8 kb0 = *(const bf16x8*)(&Kc[krow * 64 + ((0 + g) ^ swz) * 8]);
        bf16x8 kb1 = *(const bf16x8*)(&Kc[krow * 64 + ((4 + g) ^ swz) * 8]);
        sc0[kf] = MFMA16(kb0, qfr[0][0], sc0[kf]);
        sc0[kf] = MFMA16(kb1, qfr[0][1], sc0[kf]);
        sc1[kf] = MFMA16(kb0, qfr[1][0], sc1[kf]);
        sc1[kf] = MFMA16(kb1, qfr[1][1], sc1[kf]);
      }
      __builtin_amdgcn_s_setprio(0);

      #pragma unroll
      for (int qi = 0; qi < 2; ++qi) {
        f32x4* sc = qi ? sc1 : sc0;
        const int qg = qrow0 + qi * 16 + lq;
        float pv[16];
        float mx = -1e30f;
        if (full) {
          #pragma unroll
          for (int i = 0; i < 16; ++i) {
            float s = sc[i >> 2][i & 3] * SC;
            pv[i] = s;
            mx = fmaxf(mx, s);
          }
        } else {
          #pragma unroll
          for (int kf = 0; kf < 4; ++kf)
            #pragma unroll
            for (int r = 0; r < 4; ++r) {
              int key = kt * 64 + kf * 16 + g * 4 + r;
              float s = (key <= qg) ? sc[kf][r] * SC : -1e30f;
              pv[kf * 4 + r] = s;
              mx = fmaxf(mx, s);
            }
        }
        mx = fmaxf(mx, __shfl_xor(mx, 16, 64));
        mx = fmaxf(mx, __shfl_xor(mx, 32, 64));
        if (!__all(mx <= mrow[qi])) {
          float mnew = fmaxf(mrow[qi], mx);
          float al = exp2a(mrow[qi] - mnew);
          lrow[qi] *= al;
          #pragma unroll
          for (int fd = 0; fd < 4; ++fd)
            #pragma unroll
            for (int r = 0; r < 4; ++r) o[fd][qi][r] *= al;
          mrow[qi] = mnew;
        }
        float rsum = 0.f;
        #pragma unroll
        for (int i = 0; i < 16; ++i) {
          float p = exp2a(pv[i] - mrow[qi]);
          pv[i] = p;
          rsum += p;
        }
        rsum += __shfl_xor(rsum, 16, 64);
        rsum += __shfl_xor(rsum, 32, 64);
        lrow[qi] += rsum;

        // P^T staging for this q-frag (wave-local, 16 rows)
        #pragma unroll
        for (int kf = 0; kf < 4; ++kf) {
          bf16x4v pk;
          #pragma unroll
          for (int r = 0; r < 4; ++r) pk[r] = (bf16)pv[kf * 4 + r];
          *(bf16x4v*)(&Ps[w][lq * 72 + kf * 16 + g * 4]) = pk;
        }
        asm volatile("" ::: "memory");
        bf16x8 pf2[2];
        #pragma unroll
        for (int ks = 0; ks < 2; ++ks)
          pf2[ks] = *(const bf16x8*)(&Ps[w][lq * 72 + ks * 32 + lk]);

        __builtin_amdgcn_s_setprio(1);
        #pragma unroll
        for (int fd = 0; fd < 4; ++fd) {
          const int drow = fd * 16 + lq;
          #pragma unroll
          for (int ks = 0; ks < 2; ++ks) {
            bf16x8 vb = *(const bf16x8*)(&Vt[drow * 64 + (((ks * 4 + g) ^ swz ^ (fd << 1)) * 8)]);
            o[fd][qi] = MFMA16(vb, pf2[ks], o[fd][qi]);
          }
        }
        __builtin_amdgcn_s_setprio(0);
        asm volatile("" ::: "memory");
      }
    }

    if (pf) {
      __syncthreads();   // all waves done reading Vt
      WRITE_V()
      __syncthreads();   // Vt + K gll for kt+2 visible
    }
    cur ^= 1;
  }

  // ---- epilogue: normalized partial O (attn layout) + (m,l) per row ----
  bf16* Obase = (z == 0) ? part0 : part1;
  #pragma unroll
  for (int qi = 0; qi < 2; ++qi) {
    float inv = (lrow[qi] > 0.f) ? 1.0f / lrow[qi] : 0.f;
    #pragma unroll
    for (int fd = 0; fd < 4; ++fd) {
      bf16x4v ov;
      #pragma unroll
      for (int r = 0; r < 4; ++r) ov[r] = (bf16)(o[fd][qi][r] * inv);
      *(bf16x4v*)(&Ps[w][lq * 72 + fd * 16 + g * 4]) = ov;
    }
    asm volatile("" ::: "memory");
    #pragma unroll
    for (int p = 0; p < 2; ++p) {
      int idx = p * 64 + l;
      int row16 = idx >> 3, c8 = idx & 7;
      bf16x8 v = *(const bf16x8*)(&Ps[w][row16 * 72 + c8 * 8]);
      *(bf16x8*)(&Obase[(size_t)(b * 2048 + q0 + w * 32 + qi * 16 + row16) * 1024 + h * 64 + c8 * 8]) = v;
    }
    if (g == 0) {
      int qrow = q0 + w * 32 + qi * 16 + lq;
      ml[((size_t)z * 32 + bh) * 2048 + qrow] = make_float2(mrow[qi], lrow[qi]);
    }
    asm volatile("" ::: "memory");
  }
}

// ---------------- combine: attn = merge(part0, part1) (in-place over part1) ----------
__global__ __launch_bounds__(256) void combine_kernel(const bf16* __restrict__ p0,
                                                      bf16* __restrict__ p1out,
                                                      const float2* __restrict__ ml) {
  int i = blockIdx.x * 256 + threadIdx.x;  // 1,048,576 threads, 4 elems each
  size_t e4 = (size_t)i * 4;
  int row = (int)(e4 >> 10), col = (int)(e4 & 1023);
  int bhq = ((row >> 11) * 16 + (col >> 6)) * 2048 + (row & 2047);
  float2 a0 = ml[bhq];
  float2 a1 = ml[65536 + bhq];
  float m = fmaxf(a0.x, a1.x);
  float w0 = exp2a(a0.x - m) * a0.y;
  float w1 = exp2a(a1.x - m) * a1.y;
  float inv = 1.0f / (w0 + w1);
  w0 *= inv;
  w1 *= inv;
  bf16x4v v0 = *(const bf16x4v*)(p0 + e4);
  bf16x4v v1 = *(const bf16x4v*)(p1out + e4);
  bf16x4v ov;
  #pragma unroll
  for (int j = 0; j < 4; ++j) ov[j] = (bf16)((float)v0[j] * w0 + (float)v1[j] * w1);
  *(bf16x4v*)(p1out + e4) = ov;
}

// ---------------- launch ----------------
extern "C" void kernel_launch(void* const* d_in, const int* in_sizes, int n_in,
                              void* d_out, int out_size, void* d_ws, size_t ws_size,
                              hipStream_t stream) {
  const float* x = (const float*)d_in[0];
  const int* pos = (const int*)d_in[1];
  const float* w_qkv = (const float*)d_in[2];
  const float* w_out = (const float*)d_in[3];
  float* out = (float*)d_out;

  char* ws = (char*)d_ws;
  bf16* xb    = (bf16*)(ws);                // 8 MB  (reused as part0 after gemm1)
  bf16* wqb   = (bf16*)(ws + (8u << 20));   // 6 MB  (reused as ml after gemm1)
  bf16* wob   = (bf16*)(ws + (14u << 20));  // 2 MB  (cast AFTER fa)
  bf16* qkv   = (bf16*)(ws + (16u << 20));  // 24 MB
  bf16* attn  = (bf16*)(ws + (40u << 20));  // 8 MB  (part1 -> combined attn in place)
  bf16* part0 = xb;
  float2* mlb = (float2*)wqb;

  cast_kernel<<<4096, 256, 0, stream>>>(x, xb, 4194304 / 4);
  cast_kernel<<<3072, 256, 0, stream>>>(w_qkv, wqb, 3145728 / 4);

  dim3 g1(3072 / 128, 4096 / 128);
  gemm_bt<false><<<g1, 256, 0, stream>>>(xb, wqb, (void*)qkv, 4096, 3072, 1024);

  rope_kernel<<<8192, 256, 0, stream>>>(qkv, pos);

  dim3 gfa(2048 / 128, 32, 2);
  fa_causal<<<gfa, 256, 0, stream>>>(qkv, part0, attn, mlb);

  cast_kernel<<<1024, 256, 0, stream>>>(w_out, wob, 1048576 / 4);

  combine_kernel<<<4096, 256, 0, stream>>>(part0, attn, mlb);

  dim3 g2(1024 / 128, 4096 / 128);
  gemm_bt<true><<<g2, 256, 0, stream>>>(attn, wob, (void*)out, 4096, 1024, 1024);
}

// Round 6
// 145.388 us; speedup vs baseline: 1.3399x; 1.3399x over previous
//
#include <hip/hip_runtime.h>

using bf16 = __bf16;
typedef __bf16 bf16x2 __attribute__((ext_vector_type(2)));
typedef __bf16 bf16x4v __attribute__((ext_vector_type(4)));
typedef __bf16 bf16x8 __attribute__((ext_vector_type(8)));
typedef float f32x4 __attribute__((ext_vector_type(4)));
typedef float floatx4 __attribute__((ext_vector_type(4)));

#define MFMA16(a, b, c) __builtin_amdgcn_mfma_f32_16x16x32_bf16((a), (b), (c), 0, 0, 0)

__device__ __forceinline__ float exp2a(float x) {
  float r;
  asm("v_exp_f32 %0, %1" : "=v"(r) : "v"(x));
  return r;
}

// ---------------- cast fp32 -> bf16 (4 elems/thread) ----------------
__global__ __launch_bounds__(256) void cast_kernel(const float* __restrict__ in,
                                                   bf16* __restrict__ out, int n4) {
  int i = blockIdx.x * 256 + threadIdx.x;
  if (i >= n4) return;
  floatx4 v = *(const floatx4*)(in + (size_t)i * 4);
  bf16x4v o;
  #pragma unroll
  for (int j = 0; j < 4; ++j) o[j] = (bf16)v[j];
  *(bf16x4v*)(out + (size_t)i * 4) = o;
}

// ---------------- GEMM: C[M][N] = A[M][K] * B[N][K]^T ----------------
template <bool OUT_F32>
__global__ __launch_bounds__(256, 2) void gemm_bt(const bf16* __restrict__ A,
                                                  const bf16* __restrict__ B,
                                                  void* __restrict__ Cv,
                                                  int M, int N, int K) {
  __shared__ bf16 As[128 * 32];
  __shared__ bf16 Bs[128 * 32];
  const int t = threadIdx.x;
  const int l = t & 63;
  const int w = t >> 6;
  const int m0 = blockIdx.y * 128;
  const int n0 = blockIdx.x * 128;
  const int wr = (w >> 1) * 64;
  const int wc = (w & 1) * 64;
  const int lr = l & 15;
  const int lk = (l >> 4) * 8;

  f32x4 acc[4][4] = {};

  const int srow = t >> 2;
  const int scol = (t & 3) * 8;

  for (int k0 = 0; k0 < K; k0 += 32) {
    __syncthreads();
    #pragma unroll
    for (int j = 0; j < 2; ++j) {
      const bf16* ga = A + (size_t)(m0 + j * 64 + srow) * K + k0 + scol;
      __builtin_amdgcn_global_load_lds(
          (const __attribute__((address_space(1))) void*)ga,
          (__attribute__((address_space(3))) void*)(As + (j * 64 + srow) * 32 + scol),
          16, 0, 0);
      const bf16* gb = B + (size_t)(n0 + j * 64 + srow) * K + k0 + scol;
      __builtin_amdgcn_global_load_lds(
          (const __attribute__((address_space(1))) void*)gb,
          (__attribute__((address_space(3))) void*)(Bs + (j * 64 + srow) * 32 + scol),
          16, 0, 0);
    }
    __syncthreads();
    bf16x8 af[4], bfr[4];
    #pragma unroll
    for (int i = 0; i < 4; ++i) af[i] = *(const bf16x8*)(As + (wr + i * 16 + lr) * 32 + lk);
    #pragma unroll
    for (int i = 0; i < 4; ++i) bfr[i] = *(const bf16x8*)(Bs + (wc + i * 16 + lr) * 32 + lk);
    #pragma unroll
    for (int i = 0; i < 4; ++i)
      #pragma unroll
      for (int j = 0; j < 4; ++j)
        acc[i][j] = MFMA16(af[i], bfr[j], acc[i][j]);
  }

  const int cr0 = (l >> 4) * 4;
  const int cc = l & 15;
  #pragma unroll
  for (int i = 0; i < 4; ++i) {
    #pragma unroll
    for (int j = 0; j < 4; ++j) {
      int row = m0 + wr + i * 16 + cr0;
      int col = n0 + wc + j * 16 + cc;
      #pragma unroll
      for (int r = 0; r < 4; ++r) {
        if constexpr (OUT_F32)
          ((float*)Cv)[(size_t)(row + r) * N + col] = acc[i][j][r];
        else
          ((bf16*)Cv)[(size_t)(row + r) * N + col] = (bf16)acc[i][j][r];
      }
    }
  }
}

// ---------------- RoPE in-place on q,k of qkv [4096][3072] ----------------
__global__ __launch_bounds__(256) void rope_kernel(bf16* __restrict__ qkv,
                                                   const int* __restrict__ pos) {
  int idx = blockIdx.x * 256 + threadIdx.x;
  int i = idx & 31;
  int h = (idx >> 5) & 15;
  int row = idx >> 9;
  int s = row & 2047;
  float p = (float)pos[s];
  float freq = exp2f(-(float)i * (13.287712379549449f / 32.0f));
  float ang = p * freq;
  float sn, cs;
  sincosf(ang, &sn, &cs);
  size_t base = (size_t)row * 3072 + h * 64 + 2 * i;
  bf16x2 q = *(bf16x2*)(qkv + base);
  bf16x2 k = *(bf16x2*)(qkv + base + 1024);
  float q1 = (float)q[0], q2 = (float)q[1];
  float k1 = (float)k[0], k2 = (float)k[1];
  bf16x2 qo, ko;
  qo[0] = (bf16)(q1 * cs - q2 * sn);
  qo[1] = (bf16)(q1 * sn + q2 * cs);
  ko[0] = (bf16)(k1 * cs - k2 * sn);
  ko[1] = (bf16)(k1 * sn + k2 * cs);
  *(bf16x2*)(qkv + base) = qo;
  *(bf16x2*)(qkv + base + 1024) = ko;
}

// ---------------- causal flash attention v6: 8 waves, wave = 16 q-rows ----------------
// grid: (S/128, B*H), 512 thr = 8 waves; wave w owns q rows [q0+16w, q0+16w+16).
// KV tile 64, K and V both double-buffered. K via global_load_lds (source-XOR swizzle);
// V reg-staged with bijective XOR (2-way-free writes). One barrier per tile.
// Swapped-operand MFMA, lane-local exp2 softmax, defer-max.
__global__ __launch_bounds__(512, 4) void fa_causal(const bf16* __restrict__ qkv,
                                                    bf16* __restrict__ attn) {
  const int bh = blockIdx.y;
  const int b = bh >> 4, h = bh & 15;
  const int q0 = ((int)gridDim.x - 1 - (int)blockIdx.x) * 128;  // heavy blocks first
  const int t = threadIdx.x, w = t >> 6, l = t & 63;
  const int lq = l & 15;
  const int g = l >> 4;
  const int lk = g * 8;
  const int swz = lq & 7;
  const int hz = lq >> 3;  // high bit of lq (d-row bit 3)

  __shared__ bf16 Ks[2][64 * 64];   // K dbuf, source-XOR swizzled content
  __shared__ bf16 Vt[2][64 * 64];   // V^T dbuf, bijective XOR swizzled
  __shared__ bf16 Ps[8][16 * 72];   // per-wave P^T / epilogue staging

  const size_t rs = 3072;
  const bf16* Qg = qkv + (size_t)(b * 2048) * rs + h * 64;
  const bf16* Kg = Qg + 1024;
  const bf16* Vg = Qg + 2048;

  const int qrow0 = q0 + w * 16;
  const int qg = qrow0 + lq;

  bf16x8 qfr[2];
  #pragma unroll
  for (int kk = 0; kk < 2; ++kk)
    qfr[kk] = *(const bf16x8*)(Qg + (size_t)qg * rs + kk * 32 + lk);

  f32x4 o[4] = {};
  float mrow = -1e30f, lrow = 0.f;
  const float SC = 0.125f * 1.44269504088896f;  // scale * log2(e)

  const int nkt = (q0 + 128) >> 6;
  const int krow_in = l >> 3;            // 0..7
  const int kcsrc = (l & 7) ^ krow_in;   // pre-swizzled source chunk
  const int vk = t >> 3;                 // 0..63 key row
  const int cd = t & 7;                  // d-chunk 0..7

  bf16x8 va;

  #define STAGE_K(KT, BUF)                                                              \
    {                                                                                   \
      const int rowbase = w * 8;                                                        \
      const bf16* src = Kg + (size_t)((KT)*64 + rowbase + krow_in) * rs + kcsrc * 8;    \
      __builtin_amdgcn_global_load_lds(                                                 \
          (const __attribute__((address_space(1))) void*)src,                           \
          (__attribute__((address_space(3))) void*)(&Ks[BUF][rowbase * 64]), 16, 0, 0); \
    }
  #define LOAD_V(KT)                                                        \
    { va = *(const bf16x8*)(Vg + (size_t)((KT)*64 + vk) * rs + cd * 8); }
  #define WRITE_V(BUF)                                                      \
    {                                                                       \
      _Pragma("unroll")                                                     \
      for (int e = 0; e < 8; ++e)                                           \
        Vt[BUF][(cd * 8 + e) * 64 + (vk ^ ((e ^ cd) << 3))] = va[e];        \
    }

  STAGE_K(0, 0)
  LOAD_V(0)
  WRITE_V(0)
  __syncthreads();

  int cur = 0;
  for (int kt = 0; kt < nkt; ++kt) {
    const bool pf = (kt + 1 < nkt);
    if (pf) {
      LOAD_V(kt + 1)
      STAGE_K(kt + 1, cur ^ 1)
    }

    if (kt * 64 <= qrow0 + 15) {  // wave-uniform causal skip
      const bf16* Kc = Ks[cur];
      const bf16* Vc = Vt[cur];
      const bool full = (kt * 64 + 63 <= qg) | (kt * 64 + 63 <= qrow0 + 15 ? 0 : 0);
      const bool fullw = (kt * 64 + 63 <= qrow0);  // wave-uniform: no mask anywhere

      f32x4 sc[4] = {};
      __builtin_amdgcn_s_setprio(1);
      #pragma unroll
      for (int kf = 0; kf < 4; ++kf) {
        const int krow = kf * 16 + lq;
        bf16x8 kb0 = *(const bf16x8*)(&Kc[krow * 64 + ((0 + g) ^ swz) * 8]);
        bf16x8 kb1 = *(const bf16x8*)(&Kc[krow * 64 + ((4 + g) ^ swz) * 8]);
        sc[kf] = MFMA16(kb0, qfr[0], sc[kf]);
        sc[kf] = MFMA16(kb1, qfr[1], sc[kf]);
      }
      __builtin_amdgcn_s_setprio(0);

      float pv[16];
      float mx = -1e30f;
      if (fullw) {
        #pragma unroll
        for (int i = 0; i < 16; ++i) {
          float s = sc[i >> 2][i & 3] * SC;
          pv[i] = s;
          mx = fmaxf(mx, s);
        }
      } else {
        #pragma unroll
        for (int kf = 0; kf < 4; ++kf)
          #pragma unroll
          for (int r = 0; r < 4; ++r) {
            int key = kt * 64 + kf * 16 + g * 4 + r;
            float s = (key <= qg) ? sc[kf][r] * SC : -1e30f;
            pv[kf * 4 + r] = s;
            mx = fmaxf(mx, s);
          }
      }
      mx = fmaxf(mx, __shfl_xor(mx, 16, 64));
      mx = fmaxf(mx, __shfl_xor(mx, 32, 64));
      if (!__all(mx <= mrow)) {  // defer-max
        float mnew = fmaxf(mrow, mx);
        float al = exp2a(mrow - mnew);
        lrow *= al;
        #pragma unroll
        for (int fd = 0; fd < 4; ++fd)
          #pragma unroll
          for (int r = 0; r < 4; ++r) o[fd][r] *= al;
        mrow = mnew;
      }
      float rsum = 0.f;
      #pragma unroll
      for (int i = 0; i < 16; ++i) {
        float p = exp2a(pv[i] - mrow);
        pv[i] = p;
        rsum += p;
      }
      rsum += __shfl_xor(rsum, 16, 64);
      rsum += __shfl_xor(rsum, 32, 64);
      lrow += rsum;

      // P^T relayout (wave-local)
      #pragma unroll
      for (int kf = 0; kf < 4; ++kf) {
        bf16x4v pk;
        #pragma unroll
        for (int r = 0; r < 4; ++r) pk[r] = (bf16)pv[kf * 4 + r];
        *(bf16x4v*)(&Ps[w][lq * 72 + kf * 16 + g * 4]) = pk;
      }
      asm volatile("" ::: "memory");
      bf16x8 pf2[2];
      #pragma unroll
      for (int ks = 0; ks < 2; ++ks)
        pf2[ks] = *(const bf16x8*)(&Ps[w][lq * 72 + ks * 32 + lk]);

      __builtin_amdgcn_s_setprio(1);
      #pragma unroll
      for (int fd = 0; fd < 4; ++fd) {
        const int drow = fd * 16 + lq;
        #pragma unroll
        for (int ks = 0; ks < 2; ++ks) {
          int pc = (ks * 4 + g) ^ swz ^ (fd << 1) ^ hz;
          bf16x8 vb = *(const bf16x8*)(&Vc[drow * 64 + pc * 8]);
          o[fd] = MFMA16(vb, pf2[ks], o[fd]);
        }
      }
      __builtin_amdgcn_s_setprio(0);
    }

    if (pf) {
      WRITE_V(cur ^ 1)   // writes other buffer: safe before barrier
      __syncthreads();   // publishes V stores + K gll for tile kt+1
    }
    cur ^= 1;
  }

  // ---- epilogue: O^T -> [q][d] via per-wave LDS -> coalesced b128 stores ----
  float inv = 1.0f / lrow;
  #pragma unroll
  for (int fd = 0; fd < 4; ++fd) {
    bf16x4v ov;
    #pragma unroll
    for (int r = 0; r < 4; ++r) ov[r] = (bf16)(o[fd][r] * inv);
    *(bf16x4v*)(&Ps[w][lq * 72 + fd * 16 + g * 4]) = ov;
  }
  asm volatile("" ::: "memory");
  #pragma unroll
  for (int p = 0; p < 2; ++p) {
    int idx = p * 64 + l;
    int row16 = idx >> 3, c8 = idx & 7;
    bf16x8 v = *(const bf16x8*)(&Ps[w][row16 * 72 + c8 * 8]);
    *(bf16x8*)(&attn[(size_t)(b * 2048 + qrow0 + row16) * 1024 + h * 64 + c8 * 8]) = v;
  }
}

// ---------------- launch ----------------
extern "C" void kernel_launch(void* const* d_in, const int* in_sizes, int n_in,
                              void* d_out, int out_size, void* d_ws, size_t ws_size,
                              hipStream_t stream) {
  const float* x = (const float*)d_in[0];
  const int* pos = (const int*)d_in[1];
  const float* w_qkv = (const float*)d_in[2];
  const float* w_out = (const float*)d_in[3];
  float* out = (float*)d_out;

  char* ws = (char*)d_ws;
  bf16* xb   = (bf16*)(ws);
  bf16* wqb  = (bf16*)(ws + (8u << 20));
  bf16* wob  = (bf16*)(ws + (14u << 20));
  bf16* qkv  = (bf16*)(ws + (16u << 20));
  bf16* attn = (bf16*)(ws + (40u << 20));

  cast_kernel<<<4096, 256, 0, stream>>>(x, xb, 4194304 / 4);
  cast_kernel<<<3072, 256, 0, stream>>>(w_qkv, wqb, 3145728 / 4);
  cast_kernel<<<1024, 256, 0, stream>>>(w_out, wob, 1048576 / 4);

  dim3 g1(3072 / 128, 4096 / 128);
  gemm_bt<false><<<g1, 256, 0, stream>>>(xb, wqb, (void*)qkv, 4096, 3072, 1024);

  rope_kernel<<<8192, 256, 0, stream>>>(qkv, pos);

  dim3 gfa(2048 / 128, 32);
  fa_causal<<<gfa, 512, 0, stream>>>(qkv, attn);

  dim3 g2(1024 / 128, 4096 / 128);
  gemm_bt<true><<<g2, 256, 0, stream>>>(attn, wob, (void*)out, 4096, 1024, 1024);
}